// Round 1
// baseline (839.958 us; speedup 1.0000x reference)
//
#include <hip/hip_runtime.h>
#include <hip/hip_cooperative_groups.h>

namespace cg = cooperative_groups;

// Problem constants (from reference)
constexpr int T   = 5;
constexpr int B   = 32;
constexpr int C   = 128;
constexpr int HW  = 32 * 32;          // 1024
constexpr int NBC = B * C;            // 4096 (b,c) tiles of HW elements
constexpr int NPT = NBC * HW;         // 4,194,304 elements per timestep

constexpr int BLOCKS  = 1024;
constexpr int THREADS = 256;
constexpr int CHUNKS  = NBC / BLOCKS; // 4 (b,c) tiles per block; all same channel

// block=256, min 4 waves/EU -> <=128 VGPR -> 4 blocks/CU -> 1024 blocks grid-resident
__global__ __launch_bounds__(THREADS, 4)
void lif_kernel(const float* __restrict__ xe_g,
                const float* __restrict__ xi_g,
                const float* __restrict__ alpha_raw,
                const float* __restrict__ beta_raw,
                float* __restrict__ out,
                unsigned int* __restrict__ counts /* T*C slots in d_ws */) {
#pragma clang fp contract(off)
  const int blk = blockIdx.x;
  const int tid = threadIdx.x;
  // chunk stride is 1024 tiles == 0 mod 128, so this block touches only channel c:
  const int c = blk & (C - 1);

  // zero the per-(t,c) spike counters (d_ws is poisoned 0xAA)
  for (int i = blk * THREADS + tid; i < T * C; i += BLOCKS * THREADS)
    counts[i] = 0u;

  const float alpha = 4.0f / (1.0f + expf(-alpha_raw[0])); // 4*sigmoid
  const float beta  = 1.0f / (1.0f + expf(-beta_raw[0]));  // sigmoid

  // per-thread membrane state: 4 chunks x float4 = 16 elements, lives in VGPRs
  float mem[CHUNKS][4];
#pragma unroll
  for (int k = 0; k < CHUNKS; ++k)
#pragma unroll
    for (int j = 0; j < 4; ++j) mem[k][j] = 0.0f;

  float ema  = 0.17f; // EMA_INIT
  float inhw = 0.0f;

  cg::this_grid().sync(); // counters zeroed everywhere before t=0 atomics

  for (int t = 0; t < T; ++t) {
    unsigned int local = 0;
    const size_t tbase = (size_t)t * NPT;
#pragma unroll
    for (int k = 0; k < CHUNKS; ++k) {
      const size_t base = tbase + (size_t)(k * BLOCKS + blk) * HW + (size_t)tid * 4;
      const float4 e4 = *(const float4*)(xe_g + base);
      const float4 i4 = *(const float4*)(xi_g + base);
      const float xe[4] = {e4.x, e4.y, e4.z, e4.w};
      const float xi[4] = {i4.x, i4.y, i4.z, i4.w};
      float sv[4];
#pragma unroll
      for (int j = 0; j < 4; ++j) {
        // e_input = xe / (1 + alpha*xi)   (IEEE divide, matches np)
        const float e_in = xe[j] / (1.0f + alpha * xi[j]);
        // mem = 0.5*mem + e_input - (beta*xi)*(1-inhw)  -- literal python op order
        const float a = 0.5f * mem[k][j];
        const float b = a + e_in;
        const float d = (beta * xi[j]) * (1.0f - inhw);
        const float m = b - d;
        const float x = m - 0.5f;            // mem - V_TH
        const float s = (x >= 0.0f) ? 1.0f : 0.0f;
        local += (x >= 0.0f) ? 1u : 0u;
        mem[k][j] = m - 0.5f * s;            // soft reset
        sv[j] = s;
      }
      float4 s4;
      s4.x = sv[0]; s4.y = sv[1]; s4.z = sv[2]; s4.w = sv[3];
      *(float4*)(out + base) = s4;
    }

    // integer spike count: wave-level shuffle reduce, one atomic per wave.
    // Values are integers -> atomicAdd order-independent -> deterministic.
#pragma unroll
    for (int off = 32; off > 0; off >>= 1) local += __shfl_down(local, off);
    if ((tid & 63) == 0) atomicAdd(&counts[t * C + c], local);

    cg::this_grid().sync(); // all channel-c atomics visible to all 8 peer blocks

    // per-block (redundant per-thread) ema/inhw update for this block's channel
    const float mean_spike = (float)counts[t * C + c] * (1.0f / 32768.0f); // exact /2^15
    ema = 0.9f * ema + 0.1f * mean_spike;
    const float s_lo = 1.0f / (1.0f + expf(-(0.17f - ema)));  // sigmoid(LOWER-ema)
    const float s_hi = 1.0f / (1.0f + expf(-(ema - 0.23f)));  // sigmoid(ema-UPPER)
    inhw = 4.0f * (s_lo - s_hi);
  }
}

extern "C" void kernel_launch(void* const* d_in, const int* in_sizes, int n_in,
                              void* d_out, int out_size, void* d_ws, size_t ws_size,
                              hipStream_t stream) {
  const float* xe = (const float*)d_in[0];
  const float* xi = (const float*)d_in[1];
  const float* ar = (const float*)d_in[2];
  const float* br = (const float*)d_in[3];
  float* out = (float*)d_out;
  unsigned int* counts = (unsigned int*)d_ws; // T*C = 640 uints

  void* args[] = {(void*)&xe, (void*)&xi, (void*)&ar, (void*)&br,
                  (void*)&out, (void*)&counts};
  hipLaunchCooperativeKernel((const void*)lif_kernel, dim3(BLOCKS), dim3(THREADS),
                             args, 0, stream);
}

// Round 5
// 246.439 us; speedup vs baseline: 3.4084x; 3.4084x over previous
//
#include <hip/hip_runtime.h>

// Problem constants (from reference): x [T, B, C, H, W] = [5, 32, 128, 32, 32]
constexpr int T    = 5;
constexpr int Bn   = 32;
constexpr int C    = 128;
constexpr int HW   = 32 * 32;              // 1024
constexpr int NPT4 = Bn * C * HW / 4;      // float4s per timestep = 1,048,576

constexpr int THREADS = 1024;              // 16 waves -> one full CU per block
constexpr int WAVES   = THREADS / 64;      // 16
constexpr int F4_PER_THREAD = (Bn * HW / 4) / THREADS; // 8192/1024 = 8

// ONE BLOCK PER CHANNEL: the ema/inhw recurrence couples elements only within
// a channel, so with block c owning all 32768 elements of channel c the whole
// scan is block-local — no cooperative launch, no grid sync, no workspace.
// (R1's cooperative version passed at 700us, barrier-bound; R2-R4's custom
// inter-block barriers all failed at the launch path. This removes the need.)
// 1024-thread block forces the compiler to <=128 VGPR automatically.
__global__ __launch_bounds__(THREADS)
void lif_kernel(const float* __restrict__ xe_g,
                const float* __restrict__ xi_g,
                const float* __restrict__ alpha_raw,
                const float* __restrict__ beta_raw,
                float* __restrict__ out) {
#pragma clang fp contract(off)
  const int c    = blockIdx.x;   // channel
  const int tid  = threadIdx.x;
  const int wave = tid >> 6;
  const int lane = tid & 63;

  // per-(t,wave) partial spike counts; distinct slots per t -> ONE sync per t
  __shared__ unsigned int wsum[T - 1][WAVES];

  const float alpha = 4.0f / (1.0f + expf(-alpha_raw[0])); // 4*sigmoid(0)
  const float beta  = 1.0f / (1.0f + expf(-beta_raw[0]));  // sigmoid(0)

  // membrane state: 8 float4 = 32 VGPRs, lives in registers for all 5 steps
  float mem[F4_PER_THREAD][4];
#pragma unroll
  for (int k = 0; k < F4_PER_THREAD; ++k)
#pragma unroll
    for (int j = 0; j < 4; ++j) mem[k][j] = 0.0f;

  float ema  = 0.17f; // EMA_INIT
  float inhw = 0.0f;

  // float4-index for (k): g = k*1024 + tid in [0,8192); tile b = g>>8 (256 f4
  // per (b,c) tile), within-tile offset = g&255. Consecutive tids ->
  // consecutive addresses (coalesced in 256-thread segments).
  const float4* xe4 = (const float4*)xe_g;
  const float4* xi4 = (const float4*)xi_g;
  float4*       o4  = (float4*)out;

  for (int t = 0; t < T; ++t) {
    unsigned int local = 0;
    const size_t tbase = (size_t)t * NPT4;
#pragma unroll
    for (int k = 0; k < F4_PER_THREAD; ++k) {
      const int g   = k * THREADS + tid;
      const int b   = g >> 8;
      const int off = g & 255;
      const size_t idx = tbase + (size_t)(b * C + c) * 256 + off;
      const float4 e4 = xe4[idx];
      const float4 i4 = xi4[idx];
      const float xe[4] = {e4.x, e4.y, e4.z, e4.w};
      const float xi[4] = {i4.x, i4.y, i4.z, i4.w};
      float sv[4];
#pragma unroll
      for (int j = 0; j < 4; ++j) {
        // identical arithmetic to R1 (absmax was exactly 0.0):
        // e_input = xe / (1 + alpha*xi); literal python op order, contract off
        const float e_in = xe[j] / (1.0f + alpha * xi[j]);
        const float a = 0.5f * mem[k][j];
        const float bb = a + e_in;
        const float d = (beta * xi[j]) * (1.0f - inhw);
        const float m = bb - d;
        const float x = m - 0.5f;            // mem - V_TH
        const float s = (x >= 0.0f) ? 1.0f : 0.0f;
        local += (x >= 0.0f) ? 1u : 0u;
        mem[k][j] = m - 0.5f * s;            // soft reset
        sv[j] = s;
      }
      float4 s4;
      s4.x = sv[0]; s4.y = sv[1]; s4.z = sv[2]; s4.w = sv[3];
      o4[idx] = s4;
    }

    if (t == T - 1) break; // last ema/inhw update is never read

    // block-local reduction: wave shuffle-reduce -> LDS -> everyone sums 16
#pragma unroll
    for (int off = 32; off > 0; off >>= 1) local += __shfl_down(local, off);
    if (lane == 0) wsum[t][wave] = local;
    __syncthreads();
    unsigned int total = 0;
#pragma unroll
    for (int w = 0; w < WAVES; ++w) total += wsum[t][w]; // broadcast reads
    // (no second sync needed: next t writes wsum[t+1][*], different addresses)

    const float mean_spike = (float)total * (1.0f / 32768.0f); // exact /2^15
    ema = 0.9f * ema + 0.1f * mean_spike;
    const float s_lo = 1.0f / (1.0f + expf(-(0.17f - ema)));  // sigmoid(LOWER-ema)
    const float s_hi = 1.0f / (1.0f + expf(-(ema - 0.23f)));  // sigmoid(ema-UPPER)
    inhw = 4.0f * (s_lo - s_hi);
  }
}

extern "C" void kernel_launch(void* const* d_in, const int* in_sizes, int n_in,
                              void* d_out, int out_size, void* d_ws, size_t ws_size,
                              hipStream_t stream) {
  const float* xe = (const float*)d_in[0];
  const float* xi = (const float*)d_in[1];
  const float* ar = (const float*)d_in[2];
  const float* br = (const float*)d_in[3];
  float* out = (float*)d_out;

  // single plain launch: no workspace, no helper kernels, no cooperative API
  lif_kernel<<<dim3(C), dim3(THREADS), 0, stream>>>(xe, xi, ar, br, out);
}